// Round 2
// baseline (400.425 us; speedup 1.0000x reference)
//
#include <hip/hip_runtime.h>

// Problem constants
constexpr int Bn = 4, Sn = 2048, Dn = 1024, Hn = 16, DKn = 64;
constexpr int Mrows = Bn * Sn;  // 8192

typedef __attribute__((ext_vector_type(8))) short short8;
typedef __attribute__((ext_vector_type(4))) float f32x4;
typedef __attribute__((ext_vector_type(4))) unsigned int u32x4;

#define DEV __device__ __forceinline__

// fp32 -> bf16 round-to-nearest-even (branchless, inputs are finite)
DEV unsigned short f2bf(float f) {
    unsigned u = __builtin_bit_cast(unsigned, f);
    u += 0x7FFFu + ((u >> 16) & 1u);
    return (unsigned short)(u >> 16);
}
DEV unsigned pk2(float a, float b) {
    return (unsigned)f2bf(a) | ((unsigned)f2bf(b) << 16);
}

// ---------------------------------------------------------------------------
// GEMM: C[m,n] = sum_k A[m,k] * W[n,k]   (y = x @ W^T), M=8192, N=K=1024.
// 128x128 tile, BK=32, 256 threads (4 waves, 2x2 wave grid, 64x64 per wave).
// A: fp32 (converted during staging) or bf16 (ABF16). B (weights): fp32.
// OUTF32: write fp32 row-major [M,N] (final output); else scatter bf16 into
// head-major [B,H,S,DK] for the attention kernel.
// LDS rows padded to 40 shorts (80B) -> 2-way bank conflicts on b128 reads.
// ---------------------------------------------------------------------------
template <bool ABF16, bool OUTF32>
__global__ __launch_bounds__(256) void gemm_nt(const void* __restrict__ Ap,
                                               const float* __restrict__ Bw,
                                               void* __restrict__ Out) {
    __shared__ alignas(16) unsigned short As[128 * 40];
    __shared__ alignas(16) unsigned short Bs[128 * 40];

    const int tid = threadIdx.x;
    const int n0 = blockIdx.x * 128;
    const int m0 = blockIdx.y * 128;
    const int lane = tid & 63;
    const int w = tid >> 6;
    const int wm = (w >> 1) * 64, wn = (w & 1) * 64;
    const int g = lane >> 4, q15 = lane & 15;

    f32x4 acc[4][4] = {};

    const int srow = tid >> 1, shalf = tid & 1;

    for (int kk = 0; kk < Dn; kk += 32) {
        // ---- stage A tile (128 x 32) ----
        if (ABF16) {
            const unsigned short* Ab = (const unsigned short*)Ap;
            const u32x4* src =
                (const u32x4*)(Ab + (size_t)(m0 + srow) * Dn + kk + shalf * 16);
            u32x4 v0 = src[0], v1 = src[1];
            u32x4* dst = (u32x4*)(&As[srow * 40 + shalf * 16]);
            dst[0] = v0;
            dst[1] = v1;
        } else {
            const float* Af = (const float*)Ap;
            const float4* src =
                (const float4*)(Af + (size_t)(m0 + srow) * Dn + kk + shalf * 16);
            float4 a0 = src[0], a1 = src[1], a2 = src[2], a3 = src[3];
            u32x4 p0 = {pk2(a0.x, a0.y), pk2(a0.z, a0.w), pk2(a1.x, a1.y),
                        pk2(a1.z, a1.w)};
            u32x4 p1 = {pk2(a2.x, a2.y), pk2(a2.z, a2.w), pk2(a3.x, a3.y),
                        pk2(a3.z, a3.w)};
            u32x4* dst = (u32x4*)(&As[srow * 40 + shalf * 16]);
            dst[0] = p0;
            dst[1] = p1;
        }
        // ---- stage B tile (128 x 32), rows are output cols n ----
        {
            const float4* src =
                (const float4*)(Bw + (size_t)(n0 + srow) * Dn + kk + shalf * 16);
            float4 a0 = src[0], a1 = src[1], a2 = src[2], a3 = src[3];
            u32x4 p0 = {pk2(a0.x, a0.y), pk2(a0.z, a0.w), pk2(a1.x, a1.y),
                        pk2(a1.z, a1.w)};
            u32x4 p1 = {pk2(a2.x, a2.y), pk2(a2.z, a2.w), pk2(a3.x, a3.y),
                        pk2(a3.z, a3.w)};
            u32x4* dst = (u32x4*)(&Bs[srow * 40 + shalf * 16]);
            dst[0] = p0;
            dst[1] = p1;
        }
        __syncthreads();

        short8 af[4], bf[4];
#pragma unroll
        for (int mf = 0; mf < 4; ++mf)
            af[mf] = __builtin_bit_cast(
                short8, *(const u32x4*)(&As[(wm + mf * 16 + q15) * 40 + g * 8]));
#pragma unroll
        for (int nf = 0; nf < 4; ++nf)
            bf[nf] = __builtin_bit_cast(
                short8, *(const u32x4*)(&Bs[(wn + nf * 16 + q15) * 40 + g * 8]));
#pragma unroll
        for (int mf = 0; mf < 4; ++mf)
#pragma unroll
            for (int nf = 0; nf < 4; ++nf)
                acc[mf][nf] = __builtin_amdgcn_mfma_f32_16x16x32_bf16(
                    af[mf], bf[nf], acc[mf][nf], 0, 0, 0);
        __syncthreads();
    }

    // ---- epilogue: D layout col = lane&15 (n), row = 4*(lane>>4)+r (m) ----
#pragma unroll
    for (int mf = 0; mf < 4; ++mf)
#pragma unroll
        for (int nf = 0; nf < 4; ++nf)
#pragma unroll
            for (int r = 0; r < 4; ++r) {
                int m = m0 + wm + mf * 16 + 4 * g + r;
                int n = n0 + wn + nf * 16 + q15;
                float val = acc[mf][nf][r];
                if (OUTF32) {
                    ((float*)Out)[(size_t)m * Dn + n] = val;
                } else {
                    int b = m >> 11, s = m & (Sn - 1);
                    int h = n >> 6, dk = n & 63;
                    ((unsigned short*)Out)[(((size_t)(b * Hn + h) * Sn + s) << 6) +
                                           dk] = f2bf(val);
                }
            }
}

// ---------------------------------------------------------------------------
// Causal flash attention. Grid: (S/64 q-blocks, B*H). 256 threads = 4 waves,
// each wave owns 16 q rows. KV blocks of 64 staged in LDS:
//   Kt: [64 kv][64 dk] bf16, XOR-swizzled (byte ^= (row&7)<<4)
//   Vt: [64 dk][64 kv] bf16 (transposed at staging), same swizzle
// Swapped QK^T: S^T = mfma(A=K, B=Q) -> lane holds P[kv][q=lane&15];
// softmax per lane + 2 shfl_xor; P shuffled into PV A-fragment layout.
// ---------------------------------------------------------------------------
__global__ __launch_bounds__(256) void attn_fwd(const unsigned short* __restrict__ Qb,
                                                const unsigned short* __restrict__ Kb,
                                                const unsigned short* __restrict__ Vb,
                                                unsigned short* __restrict__ Xb) {
    __shared__ alignas(16) unsigned short Kt[64 * 64];
    __shared__ alignas(16) unsigned short Vt[64 * 64];

    const int tid = threadIdx.x;
    const int qblk = (int)(gridDim.x - 1) - (int)blockIdx.x;  // longest first
    const int bh = blockIdx.y;
    const int b = bh >> 4, h = bh & 15;
    const int lane = tid & 63, w = tid >> 6;
    const int g = lane >> 4, q15 = lane & 15;

    const unsigned short* Qh = Qb + (size_t)bh * Sn * DKn;
    const unsigned short* Kh = Kb + (size_t)bh * Sn * DKn;
    const unsigned short* Vh = Vb + (size_t)bh * Sn * DKn;

    const int qg = qblk * 64 + w * 16 + q15;  // this lane's q row

    short8 qf[2];
#pragma unroll
    for (int ks = 0; ks < 2; ++ks)
        qf[ks] = __builtin_bit_cast(
            short8, *(const u32x4*)(Qh + (size_t)qg * DKn + ks * 32 + g * 8));

    f32x4 xacc[4] = {};
    float m_run = -1e30f, l_run = 0.f;

    const int st_row = tid >> 2, st_seg = tid & 3;  // K staging (2 segs/thread)
    const int sv_kv = tid & 63, sv_g = tid >> 6;    // V staging

    for (int j = 0; j <= qblk; ++j) {
        // ---- stage K (row-major, swizzled): 64 rows x 128B = 8KiB.
        // 256 threads x 2 x 16B segments. seg in {st_seg, st_seg+4}.
#pragma unroll
        for (int half = 0; half < 2; ++half) {
            int seg = st_seg + half * 4;
            u32x4 kvec =
                *(const u32x4*)(Kh + (size_t)(j * 64 + st_row) * DKn + seg * 8);
            unsigned byteoff =
                ((unsigned)(st_row * 128 + seg * 16)) ^ ((unsigned)(st_row & 7) << 4);
            *(u32x4*)((char*)Kt + byteoff) = kvec;
        }
        // ---- stage V transposed (Vt[dk][kv]) ----
#pragma unroll
        for (int r2 = 0; r2 < 2; ++r2) {
            int dk0 = sv_g * 8 + r2 * 32;
            u32x4 vvec =
                *(const u32x4*)(Vh + (size_t)(j * 64 + sv_kv) * DKn + dk0);
#pragma unroll
            for (int i = 0; i < 4; ++i) {
                unsigned word = vvec[i];
                int e0 = 2 * i;
                unsigned b0 = (unsigned)((dk0 + e0) * 128 + sv_kv * 2) ^
                              ((unsigned)(e0 & 7) << 4);
                unsigned b1 = (unsigned)((dk0 + e0 + 1) * 128 + sv_kv * 2) ^
                              ((unsigned)((e0 + 1) & 7) << 4);
                *(unsigned short*)((char*)Vt + b0) = (unsigned short)(word & 0xffff);
                *(unsigned short*)((char*)Vt + b1) = (unsigned short)(word >> 16);
            }
        }
        __syncthreads();

        // ---- QK^T (swapped): sacc rows = kv, cols = q ----
        f32x4 sacc[4] = {};
#pragma unroll
        for (int mf = 0; mf < 4; ++mf) {
            int row = mf * 16 + q15;
#pragma unroll
            for (int ks = 0; ks < 2; ++ks) {
                unsigned byteoff = ((unsigned)(row * 128 + ks * 64 + g * 16)) ^
                                   ((unsigned)(row & 7) << 4);
                short8 kf =
                    __builtin_bit_cast(short8, *(const u32x4*)((char*)Kt + byteoff));
                sacc[mf] =
                    __builtin_amdgcn_mfma_f32_16x16x32_bf16(kf, qf[ks], sacc[mf], 0, 0, 0);
            }
        }

        // ---- mask + online softmax (each lane owns q row qg) ----
        float p[4][4];
        float pmax = -1e30f;
        const bool diag = (j == qblk);
#pragma unroll
        for (int mf = 0; mf < 4; ++mf)
#pragma unroll
            for (int r = 0; r < 4; ++r) {
                float sv = sacc[mf][r] * 0.125f;
                if (diag) {
                    int kvg = j * 64 + mf * 16 + 4 * g + r;
                    if (kvg > qg) sv = -1e30f;
                }
                p[mf][r] = sv;
                pmax = fmaxf(pmax, sv);
            }
        pmax = fmaxf(pmax, __shfl_xor(pmax, 16));
        pmax = fmaxf(pmax, __shfl_xor(pmax, 32));
        float mnew = fmaxf(m_run, pmax);
        float corr = __expf(m_run - mnew);
        float lsum = 0.f;
#pragma unroll
        for (int mf = 0; mf < 4; ++mf)
#pragma unroll
            for (int r = 0; r < 4; ++r) {
                float e = __expf(p[mf][r] - mnew);
                p[mf][r] = e;
                lsum += e;
            }
        lsum += __shfl_xor(lsum, 16);
        lsum += __shfl_xor(lsum, 32);
        l_run = l_run * corr + lsum;
        m_run = mnew;

        // rescale accumulator: xacc row q' = 4*g + r, state lives in lane q'
        float cr0 = __shfl(corr, 4 * g + 0);
        float cr1 = __shfl(corr, 4 * g + 1);
        float cr2 = __shfl(corr, 4 * g + 2);
        float cr3 = __shfl(corr, 4 * g + 3);
#pragma unroll
        for (int nf = 0; nf < 4; ++nf) {
            xacc[nf][0] *= cr0;
            xacc[nf][1] *= cr1;
            xacc[nf][2] *= cr2;
            xacc[nf][3] *= cr3;
        }

        // ---- pack P to bf16 pairs, shuffle into PV A-frag layout ----
        unsigned pkk[4][2];
#pragma unroll
        for (int mf = 0; mf < 4; ++mf) {
            pkk[mf][0] = pk2(p[mf][0], p[mf][1]);
            pkk[mf][1] = pk2(p[mf][2], p[mf][3]);
        }
#pragma unroll
        for (int ks = 0; ks < 2; ++ks) {
            unsigned aw[4];
#pragma unroll
            for (int rp = 0; rp < 4; ++rp) {
                int srcl = ((2 * g + (rp >> 1)) & 3) * 16 + q15;
                unsigned lo = (unsigned)__shfl((int)pkk[2 * ks][rp & 1], srcl);
                unsigned hi = (unsigned)__shfl((int)pkk[2 * ks + 1][rp & 1], srcl);
                aw[rp] = (lane & 32) ? hi : lo;
            }
            u32x4 tmp = {aw[0], aw[1], aw[2], aw[3]};
            short8 pa = __builtin_bit_cast(short8, tmp);
#pragma unroll
            for (int nf = 0; nf < 4; ++nf) {
                int row = nf * 16 + q15;
                unsigned byteoff = ((unsigned)(row * 128 + ks * 64 + g * 16)) ^
                                   ((unsigned)(row & 7) << 4);
                short8 vf =
                    __builtin_bit_cast(short8, *(const u32x4*)((char*)Vt + byteoff));
                xacc[nf] =
                    __builtin_amdgcn_mfma_f32_16x16x32_bf16(pa, vf, xacc[nf], 0, 0, 0);
            }
        }
        __syncthreads();
    }

    // ---- epilogue: normalize and write X[b,s,d] bf16 ----
    float inv = 1.0f / l_run;
    float ir[4];
    ir[0] = __shfl(inv, 4 * g + 0);
    ir[1] = __shfl(inv, 4 * g + 1);
    ir[2] = __shfl(inv, 4 * g + 2);
    ir[3] = __shfl(inv, 4 * g + 3);
#pragma unroll
    for (int nf = 0; nf < 4; ++nf)
#pragma unroll
        for (int r = 0; r < 4; ++r) {
            int qrow = qblk * 64 + w * 16 + 4 * g + r;
            int d = h * 64 + nf * 16 + q15;
            Xb[(size_t)(b * Sn + qrow) * Dn + d] = f2bf(xacc[nf][r] * ir[r]);
        }
}

// ---------------------------------------------------------------------------
// Launch. ws layout (bf16): Qb | Kb | Vb | Xb, each 8192*1024 elems = 16 MiB,
// total 64 MiB. Q/K/V head-major [B,H,S,DK]; Xb row-major [B*S, D].
// ---------------------------------------------------------------------------
extern "C" void kernel_launch(void* const* d_in, const int* in_sizes, int n_in,
                              void* d_out, int out_size, void* d_ws, size_t ws_size,
                              hipStream_t stream) {
    (void)in_sizes; (void)n_in; (void)out_size; (void)ws_size;
    const float* q = (const float*)d_in[0];
    const float* k = (const float*)d_in[1];
    const float* v = (const float*)d_in[2];
    // d_in[3] = mask (causal tril; implemented analytically)
    const float* Wq = (const float*)d_in[4];
    const float* Wk = (const float*)d_in[5];
    const float* Wv = (const float*)d_in[6];
    const float* Wo = (const float*)d_in[7];

    unsigned short* Qb = (unsigned short*)d_ws;
    unsigned short* Kb = Qb + (size_t)Mrows * Dn;
    unsigned short* Vb = Kb + (size_t)Mrows * Dn;
    unsigned short* Xb = Vb + (size_t)Mrows * Dn;

    dim3 blk(256);
    dim3 ggrid(Dn / 128, Mrows / 128);

    gemm_nt<false, false><<<ggrid, blk, 0, stream>>>((const void*)q, Wq, (void*)Qb);
    gemm_nt<false, false><<<ggrid, blk, 0, stream>>>((const void*)k, Wk, (void*)Kb);
    gemm_nt<false, false><<<ggrid, blk, 0, stream>>>((const void*)v, Wv, (void*)Vb);

    attn_fwd<<<dim3(Sn / 64, Bn * Hn), blk, 0, stream>>>(Qb, Kb, Vb, Xb);

    gemm_nt<true, true><<<ggrid, blk, 0, stream>>>((const void*)Xb, Wo, d_out);
}

// Round 5
// 302.048 us; speedup vs baseline: 1.3257x; 1.3257x over previous
//
#include <hip/hip_runtime.h>

// Problem constants
constexpr int Bn = 4, Sn = 2048, Dn = 1024, Hn = 16, DKn = 64;
constexpr int Mrows = Bn * Sn;  // 8192
constexpr int NQB = Sn / 64;    // 32 q-chunks of 64 rows

typedef __attribute__((ext_vector_type(8))) short short8;
typedef __attribute__((ext_vector_type(4))) float f32x4;
typedef __attribute__((ext_vector_type(4))) unsigned int u32x4;

#define DEV __device__ __forceinline__

// fp32 -> bf16 round-to-nearest-even (branchless, inputs are finite)
DEV unsigned short f2bf(float f) {
    unsigned u = __builtin_bit_cast(unsigned, f);
    u += 0x7FFFu + ((u >> 16) & 1u);
    return (unsigned short)(u >> 16);
}
DEV unsigned pk2(float a, float b) {
    return (unsigned)f2bf(a) | ((unsigned)f2bf(b) << 16);
}

// ---------------------------------------------------------------------------
// GEMM: C[m,n] = sum_k A[m,k] * W[n,k]   (y = x @ W^T), M=8192, N=K=1024.
// 128x128 tile, BK=32, 256 threads (4 waves, 2x2 wave grid, 64x64 per wave).
// ---------------------------------------------------------------------------
template <bool ABF16, bool OUTF32>
__global__ __launch_bounds__(256) void gemm_nt(const void* __restrict__ Ap,
                                               const float* __restrict__ Bw,
                                               void* __restrict__ Out) {
    __shared__ alignas(16) unsigned short As[128 * 40];
    __shared__ alignas(16) unsigned short Bs[128 * 40];

    const int tid = threadIdx.x;
    const int n0 = blockIdx.x * 128;
    const int m0 = blockIdx.y * 128;
    const int lane = tid & 63;
    const int w = tid >> 6;
    const int wm = (w >> 1) * 64, wn = (w & 1) * 64;
    const int g = lane >> 4, q15 = lane & 15;

    f32x4 acc[4][4] = {};

    const int srow = tid >> 1, shalf = tid & 1;

    for (int kk = 0; kk < Dn; kk += 32) {
        if (ABF16) {
            const unsigned short* Ab = (const unsigned short*)Ap;
            const u32x4* src =
                (const u32x4*)(Ab + (size_t)(m0 + srow) * Dn + kk + shalf * 16);
            u32x4 v0 = src[0], v1 = src[1];
            u32x4* dst = (u32x4*)(&As[srow * 40 + shalf * 16]);
            dst[0] = v0;
            dst[1] = v1;
        } else {
            const float* Af = (const float*)Ap;
            const float4* src =
                (const float4*)(Af + (size_t)(m0 + srow) * Dn + kk + shalf * 16);
            float4 a0 = src[0], a1 = src[1], a2 = src[2], a3 = src[3];
            u32x4 p0 = {pk2(a0.x, a0.y), pk2(a0.z, a0.w), pk2(a1.x, a1.y),
                        pk2(a1.z, a1.w)};
            u32x4 p1 = {pk2(a2.x, a2.y), pk2(a2.z, a2.w), pk2(a3.x, a3.y),
                        pk2(a3.z, a3.w)};
            u32x4* dst = (u32x4*)(&As[srow * 40 + shalf * 16]);
            dst[0] = p0;
            dst[1] = p1;
        }
        {
            const float4* src =
                (const float4*)(Bw + (size_t)(n0 + srow) * Dn + kk + shalf * 16);
            float4 a0 = src[0], a1 = src[1], a2 = src[2], a3 = src[3];
            u32x4 p0 = {pk2(a0.x, a0.y), pk2(a0.z, a0.w), pk2(a1.x, a1.y),
                        pk2(a1.z, a1.w)};
            u32x4 p1 = {pk2(a2.x, a2.y), pk2(a2.z, a2.w), pk2(a3.x, a3.y),
                        pk2(a3.z, a3.w)};
            u32x4* dst = (u32x4*)(&Bs[srow * 40 + shalf * 16]);
            dst[0] = p0;
            dst[1] = p1;
        }
        __syncthreads();

        short8 af[4], bf[4];
#pragma unroll
        for (int mf = 0; mf < 4; ++mf)
            af[mf] = __builtin_bit_cast(
                short8, *(const u32x4*)(&As[(wm + mf * 16 + q15) * 40 + g * 8]));
#pragma unroll
        for (int nf = 0; nf < 4; ++nf)
            bf[nf] = __builtin_bit_cast(
                short8, *(const u32x4*)(&Bs[(wn + nf * 16 + q15) * 40 + g * 8]));
#pragma unroll
        for (int mf = 0; mf < 4; ++mf)
#pragma unroll
            for (int nf = 0; nf < 4; ++nf)
                acc[mf][nf] = __builtin_amdgcn_mfma_f32_16x16x32_bf16(
                    af[mf], bf[nf], acc[mf][nf], 0, 0, 0);
        __syncthreads();
    }

#pragma unroll
    for (int mf = 0; mf < 4; ++mf)
#pragma unroll
        for (int nf = 0; nf < 4; ++nf)
#pragma unroll
            for (int r = 0; r < 4; ++r) {
                int m = m0 + wm + mf * 16 + 4 * g + r;
                int n = n0 + wn + nf * 16 + q15;
                float val = acc[mf][nf][r];
                if (OUTF32) {
                    ((float*)Out)[(size_t)m * Dn + n] = val;
                } else {
                    int b = m >> 11, s = m & (Sn - 1);
                    int h = n >> 6, dk = n & 63;
                    ((unsigned short*)Out)[(((size_t)(b * Hn + h) * Sn + s) << 6) +
                                           dk] = f2bf(val);
                }
            }
}

// ---------------------------------------------------------------------------
// Causal flash attention, load-balanced: grid (NQB/2 pairs, B*H). Block i
// processes q-chunks {31-i, i} -> uniform 33 KV-iterations per block.
// 256 threads = 4 waves, each wave owns 16 q rows of the 64-row chunk.
// LDS per KV block of 64:
//   Kt: [64 kv][64 dk] bf16, XOR-swizzled (byte ^= (row&7)<<4)
//   Vt: [64 dk][64 kv] bf16 (transposed at staging via kv-pair shfl trick)
// QK^T swapped: sacc = mfma(A=K, B=Q) -> lane (g,q15) holds
// S^T[kv=mf*16+4g+r][q=q15]; softmax state m/l lives per-lane (q=q15).
// PV swapped too: O^T = mfma(A=Vt rows, B=P^T). B-frag gather: shuffle BOTH
// mf candidates with lane-invariant indices, select on dest g (shfl returns
// the SOURCE lane's evaluation of the expression — indices must not depend
// on the destination lane's registers!).
// ---------------------------------------------------------------------------
__global__ __launch_bounds__(256) void attn_fwd(const unsigned short* __restrict__ Qb,
                                                const unsigned short* __restrict__ Kb,
                                                const unsigned short* __restrict__ Vb,
                                                unsigned short* __restrict__ Xb) {
    __shared__ alignas(16) unsigned short Kt[64 * 64];
    __shared__ alignas(16) unsigned short Vt[64 * 64];

    const int tid = threadIdx.x;
    const int pair = blockIdx.x;  // 0..15
    const int bh = blockIdx.y;
    const int b = bh >> 4, h = bh & 15;
    const int lane = tid & 63, w = tid >> 6;
    const int g = lane >> 4, q15 = lane & 15;

    const unsigned short* Qh = Qb + (size_t)bh * Sn * DKn;
    const unsigned short* Kh = Kb + (size_t)bh * Sn * DKn;
    const unsigned short* Vh = Vb + (size_t)bh * Sn * DKn;

    const int st_row = tid >> 2, st_seg = tid & 3;  // K staging
    const int sv_kv = tid & 63, sv_g = tid >> 6;    // V staging
    const int sel = sv_kv & 1;
    const unsigned kvp = (unsigned)((sv_kv & ~1) * 2);  // byte col base in Vt

    for (int hp = 0; hp < 2; ++hp) {
        const int qblk = hp == 0 ? (NQB - 1 - pair) : pair;
        const int qg = qblk * 64 + w * 16 + q15;  // this lane's q row

        short8 qf[2];
#pragma unroll
        for (int ks = 0; ks < 2; ++ks)
            qf[ks] = __builtin_bit_cast(
                short8, *(const u32x4*)(Qh + (size_t)qg * DKn + ks * 32 + g * 8));

        f32x4 xacc[4] = {};  // O^T: xacc[mf][r] = O[q=q15][d=mf*16+4g+r]
        float m_run = -1e30f, l_run = 0.f;

        for (int j = 0; j <= qblk; ++j) {
            // ---- stage K (row-major, swizzled): 64x128B, 2x16B per thread ----
#pragma unroll
            for (int half2 = 0; half2 < 2; ++half2) {
                int seg = st_seg + half2 * 4;
                u32x4 kvec =
                    *(const u32x4*)(Kh + (size_t)(j * 64 + st_row) * DKn + seg * 8);
                unsigned byteoff = ((unsigned)(st_row * 128 + seg * 16)) ^
                                   ((unsigned)(st_row & 7) << 4);
                *(u32x4*)((char*)Kt + byteoff) = kvec;
            }
            // ---- stage V transposed: kv-pair trick, 8 ds_write_b32/thread ----
#pragma unroll
            for (int r2 = 0; r2 < 2; ++r2) {
                int dk0 = sv_g * 8 + r2 * 32;
                u32x4 vvec =
                    *(const u32x4*)(Vh + (size_t)(j * 64 + sv_kv) * DKn + dk0);
#pragma unroll
                for (int i = 0; i < 4; ++i) {
                    unsigned mine = vvec[i];
                    unsigned theirs = (unsigned)__shfl_xor((int)mine, 1);
                    int dk_abs = dk0 + 2 * i + sel;
                    unsigned out = sel ? ((theirs >> 16) | (mine & 0xffff0000u))
                                       : ((mine & 0xffffu) | (theirs << 16));
                    unsigned byteoff = ((unsigned)(dk_abs * 128) + kvp) ^
                                       ((unsigned)(dk_abs & 7) << 4);
                    *(unsigned*)((char*)Vt + byteoff) = out;
                }
            }
            __syncthreads();

            // ---- QK^T (swapped): sacc rows = kv, cols = q ----
            f32x4 sacc[4] = {};
#pragma unroll
            for (int mf = 0; mf < 4; ++mf) {
                int row = mf * 16 + q15;
#pragma unroll
                for (int ks = 0; ks < 2; ++ks) {
                    unsigned byteoff = ((unsigned)(row * 128 + ks * 64 + g * 16)) ^
                                       ((unsigned)(row & 7) << 4);
                    short8 kf = __builtin_bit_cast(
                        short8, *(const u32x4*)((char*)Kt + byteoff));
                    sacc[mf] = __builtin_amdgcn_mfma_f32_16x16x32_bf16(
                        kf, qf[ks], sacc[mf], 0, 0, 0);
                }
            }

            // ---- mask + online softmax (lane owns q row qg) ----
            float p[4][4];
            float pmax = -1e30f;
            const bool diag = (j == qblk);
#pragma unroll
            for (int mf = 0; mf < 4; ++mf)
#pragma unroll
                for (int r = 0; r < 4; ++r) {
                    float sv = sacc[mf][r] * 0.125f;
                    if (diag) {
                        int kvg = j * 64 + mf * 16 + 4 * g + r;
                        if (kvg > qg) sv = -1e30f;
                    }
                    p[mf][r] = sv;
                    pmax = fmaxf(pmax, sv);
                }
            pmax = fmaxf(pmax, __shfl_xor(pmax, 16));
            pmax = fmaxf(pmax, __shfl_xor(pmax, 32));
            float mnew = fmaxf(m_run, pmax);
            float corr = __expf(m_run - mnew);
            float lsum = 0.f;
#pragma unroll
            for (int mf = 0; mf < 4; ++mf)
#pragma unroll
                for (int r = 0; r < 4; ++r) {
                    float e = __expf(p[mf][r] - mnew);
                    p[mf][r] = e;
                    lsum += e;
                }
            lsum += __shfl_xor(lsum, 16);
            lsum += __shfl_xor(lsum, 32);
            l_run = l_run * corr + lsum;
            m_run = mnew;

            // rescale own-q accumulator (no shuffles)
#pragma unroll
            for (int mf = 0; mf < 4; ++mf)
#pragma unroll
                for (int r = 0; r < 4; ++r) xacc[mf][r] *= corr;

            // ---- pack P pairs; PV as O^T = mfma(A=Vt, B=P^T) ----
            unsigned pkk[4][2];
#pragma unroll
            for (int mf = 0; mf < 4; ++mf) {
                pkk[mf][0] = pk2(p[mf][0], p[mf][1]);
                pkk[mf][1] = pk2(p[mf][2], p[mf][3]);
            }
#pragma unroll
            for (int ks = 0; ks < 2; ++ks) {
                unsigned bw[4];
#pragma unroll
                for (int w2 = 0; w2 < 4; ++w2) {
                    // dest (g,q15) needs P[q15][kv=ks*32+g*8+2*w2,+1] which is
                    // pkk[2*ks+(g>>1)][w2&1] of lane g_src=2*(g&1)+(w2>>1).
                    // Shuffle BOTH mf candidates (lane-invariant indices),
                    // select on dest side.
                    int srcl = (2 * (g & 1) + (w2 >> 1)) * 16 + q15;
                    unsigned v0 = (unsigned)__shfl((int)pkk[2 * ks][w2 & 1], srcl);
                    unsigned v1 =
                        (unsigned)__shfl((int)pkk[2 * ks + 1][w2 & 1], srcl);
                    bw[w2] = (g & 2) ? v1 : v0;
                }
                u32x4 tmp = {bw[0], bw[1], bw[2], bw[3]};
                short8 pb = __builtin_bit_cast(short8, tmp);
#pragma unroll
                for (int mf = 0; mf < 4; ++mf) {
                    int row = mf * 16 + q15;
                    unsigned byteoff = ((unsigned)(row * 128 + ks * 64 + g * 16)) ^
                                       ((unsigned)(row & 7) << 4);
                    short8 vf = __builtin_bit_cast(
                        short8, *(const u32x4*)((char*)Vt + byteoff));
                    xacc[mf] = __builtin_amdgcn_mfma_f32_16x16x32_bf16(
                        vf, pb, xacc[mf], 0, 0, 0);
                }
            }
            __syncthreads();
        }

        // ---- epilogue: lane owns q=q15 row; 4x 8B stores ----
        float inv = 1.0f / l_run;
        size_t rowbase = (size_t)(b * Sn + qblk * 64 + w * 16 + q15) * Dn + h * 64;
#pragma unroll
        for (int mf = 0; mf < 4; ++mf) {
            unsigned w0 = pk2(xacc[mf][0] * inv, xacc[mf][1] * inv);
            unsigned w1 = pk2(xacc[mf][2] * inv, xacc[mf][3] * inv);
            uint2 val = {w0, w1};
            *(uint2*)(Xb + rowbase + mf * 16 + 4 * g) = val;
        }
    }
}

// ---------------------------------------------------------------------------
// Launch. ws layout (bf16): Qb | Kb | Vb | Xb, each 8192*1024 elems = 16 MiB.
// Q/K/V head-major [B,H,S,DK]; Xb row-major [B*S, D].
// ---------------------------------------------------------------------------
extern "C" void kernel_launch(void* const* d_in, const int* in_sizes, int n_in,
                              void* d_out, int out_size, void* d_ws, size_t ws_size,
                              hipStream_t stream) {
    (void)in_sizes; (void)n_in; (void)out_size; (void)ws_size;
    const float* q = (const float*)d_in[0];
    const float* k = (const float*)d_in[1];
    const float* v = (const float*)d_in[2];
    // d_in[3] = mask (causal tril; implemented analytically)
    const float* Wq = (const float*)d_in[4];
    const float* Wk = (const float*)d_in[5];
    const float* Wv = (const float*)d_in[6];
    const float* Wo = (const float*)d_in[7];

    unsigned short* Qb = (unsigned short*)d_ws;
    unsigned short* Kb = Qb + (size_t)Mrows * Dn;
    unsigned short* Vb = Kb + (size_t)Mrows * Dn;
    unsigned short* Xb = Vb + (size_t)Mrows * Dn;

    dim3 blk(256);
    dim3 ggrid(Dn / 128, Mrows / 128);

    gemm_nt<false, false><<<ggrid, blk, 0, stream>>>((const void*)q, Wq, (void*)Qb);
    gemm_nt<false, false><<<ggrid, blk, 0, stream>>>((const void*)k, Wk, (void*)Kb);
    gemm_nt<false, false><<<ggrid, blk, 0, stream>>>((const void*)v, Wv, (void*)Vb);

    attn_fwd<<<dim3(NQB / 2, Bn * Hn), blk, 0, stream>>>(Qb, Kb, Vb, Xb);

    gemm_nt<true, true><<<ggrid, blk, 0, stream>>>((const void*)Xb, Wo, d_out);
}

// Round 6
// 275.747 us; speedup vs baseline: 1.4521x; 1.0954x over previous
//
#include <hip/hip_runtime.h>
#include <hip/hip_bf16.h>

// Problem constants
constexpr int Bn = 4, Sn = 2048, Dn = 1024, Hn = 16, DKn = 64;
constexpr int Mrows = Bn * Sn;  // 8192
constexpr int NQB = Sn / 64;    // 32 q-chunks of 64 rows

typedef __attribute__((ext_vector_type(8))) short short8;
typedef __attribute__((ext_vector_type(4))) float f32x4;
typedef __attribute__((ext_vector_type(4))) unsigned int u32x4;

#define DEV __device__ __forceinline__

// fp32 -> bf16 RNE, scalar (epilogue scatter only)
DEV unsigned short f2bf(float f) {
    unsigned u = __builtin_bit_cast(unsigned, f);
    u += 0x7FFFu + ((u >> 16) & 1u);
    return (unsigned short)(u >> 16);
}
// fp32 pair -> packed bf16x2 via v_cvt_pk_bf16_f32 (hardware RNE)
DEV unsigned pk2(float a, float b) {
    __hip_bfloat162 h = __float22bfloat162_rn(float2{a, b});
    unsigned u;
    __builtin_memcpy(&u, &h, 4);
    return u;
}
// 2^x via v_exp_f32
DEV float exp2a(float x) {
    float r;
    asm("v_exp_f32 %0, %1" : "=v"(r) : "v"(x));
    return r;
}

// ---------------------------------------------------------------------------
// GEMM: C[m,n] = sum_k A[m,k] * W[n,k]   (y = x @ W^T), M=8192, N=K=1024.
// 128x128 tile, BK=32, 256 threads (4 waves, 2x2 wave grid, 64x64 per wave).
// T14 prefetch: global loads for K-step kk+32 issued right after the first
// barrier, in flight during compute of kk.
// ---------------------------------------------------------------------------
template <bool ABF16, bool OUTF32>
__global__ __launch_bounds__(256) void gemm_nt(const void* __restrict__ Ap,
                                               const float* __restrict__ Bw,
                                               void* __restrict__ Out) {
    __shared__ alignas(16) unsigned short As[128 * 40];
    __shared__ alignas(16) unsigned short Bs[128 * 40];

    const int tid = threadIdx.x;
    const int n0 = blockIdx.x * 128;
    const int m0 = blockIdx.y * 128;
    const int lane = tid & 63;
    const int w = tid >> 6;
    const int wm = (w >> 1) * 64, wn = (w & 1) * 64;
    const int g = lane >> 4, q15 = lane & 15;

    f32x4 acc[4][4] = {};

    const int srow = tid >> 1, shalf = tid & 1;

    const float* Af = (const float*)Ap;
    const unsigned short* Ab = (const unsigned short*)Ap;

    // staging registers
    float4 fa0, fa1, fa2, fa3, fb0, fb1, fb2, fb3;
    u32x4 ua0, ua1;

    auto loadA = [&](int kk) {
        if constexpr (ABF16) {
            const u32x4* s =
                (const u32x4*)(Ab + (size_t)(m0 + srow) * Dn + kk + shalf * 16);
            ua0 = s[0];
            ua1 = s[1];
        } else {
            const float4* s =
                (const float4*)(Af + (size_t)(m0 + srow) * Dn + kk + shalf * 16);
            fa0 = s[0]; fa1 = s[1]; fa2 = s[2]; fa3 = s[3];
        }
    };
    auto loadB = [&](int kk) {
        const float4* s =
            (const float4*)(Bw + (size_t)(n0 + srow) * Dn + kk + shalf * 16);
        fb0 = s[0]; fb1 = s[1]; fb2 = s[2]; fb3 = s[3];
    };
    auto store = [&]() {
        u32x4* da = (u32x4*)(&As[srow * 40 + shalf * 16]);
        if constexpr (ABF16) {
            da[0] = ua0;
            da[1] = ua1;
        } else {
            u32x4 p0 = {pk2(fa0.x, fa0.y), pk2(fa0.z, fa0.w), pk2(fa1.x, fa1.y),
                        pk2(fa1.z, fa1.w)};
            u32x4 p1 = {pk2(fa2.x, fa2.y), pk2(fa2.z, fa2.w), pk2(fa3.x, fa3.y),
                        pk2(fa3.z, fa3.w)};
            da[0] = p0;
            da[1] = p1;
        }
        u32x4* db = (u32x4*)(&Bs[srow * 40 + shalf * 16]);
        u32x4 q0 = {pk2(fb0.x, fb0.y), pk2(fb0.z, fb0.w), pk2(fb1.x, fb1.y),
                    pk2(fb1.z, fb1.w)};
        u32x4 q1 = {pk2(fb2.x, fb2.y), pk2(fb2.z, fb2.w), pk2(fb3.x, fb3.y),
                    pk2(fb3.z, fb3.w)};
        db[0] = q0;
        db[1] = q1;
    };

    loadA(0);
    loadB(0);
    for (int kk = 0; kk < Dn; kk += 32) {
        store();
        __syncthreads();
        if (kk + 32 < Dn) {
            loadA(kk + 32);
            loadB(kk + 32);
        }

        short8 af[4], bf[4];
#pragma unroll
        for (int mf = 0; mf < 4; ++mf)
            af[mf] = __builtin_bit_cast(
                short8, *(const u32x4*)(&As[(wm + mf * 16 + q15) * 40 + g * 8]));
#pragma unroll
        for (int nf = 0; nf < 4; ++nf)
            bf[nf] = __builtin_bit_cast(
                short8, *(const u32x4*)(&Bs[(wn + nf * 16 + q15) * 40 + g * 8]));
#pragma unroll
        for (int mf = 0; mf < 4; ++mf)
#pragma unroll
            for (int nf = 0; nf < 4; ++nf)
                acc[mf][nf] = __builtin_amdgcn_mfma_f32_16x16x32_bf16(
                    af[mf], bf[nf], acc[mf][nf], 0, 0, 0);
        __syncthreads();
    }

#pragma unroll
    for (int mf = 0; mf < 4; ++mf)
#pragma unroll
        for (int nf = 0; nf < 4; ++nf)
#pragma unroll
            for (int r = 0; r < 4; ++r) {
                int m = m0 + wm + mf * 16 + 4 * g + r;
                int n = n0 + wn + nf * 16 + q15;
                float val = acc[mf][nf][r];
                if (OUTF32) {
                    ((float*)Out)[(size_t)m * Dn + n] = val;
                } else {
                    int b = m >> 11, s = m & (Sn - 1);
                    int h = n >> 6, dk = n & 63;
                    ((unsigned short*)Out)[(((size_t)(b * Hn + h) * Sn + s) << 6) +
                                           dk] = f2bf(val);
                }
            }
}

// ---------------------------------------------------------------------------
// Causal flash attention, load-balanced: grid (NQB/2 pairs, B*H). Block i
// processes q-chunks {31-i, i} -> uniform 33 KV-iterations per block.
// Softmax in log2 domain (scale folded: 0.125*log2e), raw v_exp_f32,
// T13 defer-max (THR=8), T14 prefetch of next KV tile during compute.
// ---------------------------------------------------------------------------
__global__ __launch_bounds__(256) void attn_fwd(const unsigned short* __restrict__ Qb,
                                                const unsigned short* __restrict__ Kb,
                                                const unsigned short* __restrict__ Vb,
                                                unsigned short* __restrict__ Xb) {
    __shared__ alignas(16) unsigned short Kt[64 * 64];
    __shared__ alignas(16) unsigned short Vt[64 * 64];

    constexpr float SCL = 0.18033688f;  // 0.125 * log2(e)

    const int tid = threadIdx.x;
    const int pair = blockIdx.x;  // 0..15
    const int bh = blockIdx.y;
    const int b = bh >> 4, h = bh & 15;
    const int lane = tid & 63, w = tid >> 6;
    const int g = lane >> 4, q15 = lane & 15;

    const unsigned short* Qh = Qb + (size_t)bh * Sn * DKn;
    const unsigned short* Kh = Kb + (size_t)bh * Sn * DKn;
    const unsigned short* Vh = Vb + (size_t)bh * Sn * DKn;

    const int st_row = tid >> 2, st_seg = tid & 3;  // K staging
    const int sv_kv = tid & 63, sv_g = tid >> 6;    // V staging
    const int sel = sv_kv & 1;
    const unsigned kvp = (unsigned)((sv_kv & ~1) * 2);  // byte col base in Vt

    u32x4 kr0, kr1, vr0, vr1;  // prefetch registers
    auto load_kv = [&](int j) {
        kr0 = *(const u32x4*)(Kh + (size_t)(j * 64 + st_row) * DKn + st_seg * 8);
        kr1 = *(const u32x4*)(Kh + (size_t)(j * 64 + st_row) * DKn +
                              (st_seg + 4) * 8);
        vr0 = *(const u32x4*)(Vh + (size_t)(j * 64 + sv_kv) * DKn + sv_g * 8);
        vr1 = *(const u32x4*)(Vh + (size_t)(j * 64 + sv_kv) * DKn + sv_g * 8 + 32);
    };

    for (int hp = 0; hp < 2; ++hp) {
        const int qblk = hp == 0 ? (NQB - 1 - pair) : pair;
        const int qg = qblk * 64 + w * 16 + q15;  // this lane's q row

        short8 qf[2];
#pragma unroll
        for (int ks = 0; ks < 2; ++ks)
            qf[ks] = __builtin_bit_cast(
                short8, *(const u32x4*)(Qh + (size_t)qg * DKn + ks * 32 + g * 8));

        f32x4 xacc[4] = {};  // O^T: xacc[mf][r] = O[q=q15][d=mf*16+4g+r]
        float m_run = -1e30f, l_run = 0.f;

        load_kv(0);
        for (int j = 0; j <= qblk; ++j) {
            // ---- write staged KV regs to LDS ----
            {
                unsigned b0 = ((unsigned)(st_row * 128 + st_seg * 16)) ^
                              ((unsigned)(st_row & 7) << 4);
                unsigned b1 = ((unsigned)(st_row * 128 + (st_seg + 4) * 16)) ^
                              ((unsigned)(st_row & 7) << 4);
                *(u32x4*)((char*)Kt + b0) = kr0;
                *(u32x4*)((char*)Kt + b1) = kr1;
            }
#pragma unroll
            for (int r2 = 0; r2 < 2; ++r2) {
                u32x4 vvec = r2 ? vr1 : vr0;
                int dk0 = sv_g * 8 + r2 * 32;
#pragma unroll
                for (int i = 0; i < 4; ++i) {
                    unsigned mine = vvec[i];
                    unsigned theirs = (unsigned)__shfl_xor((int)mine, 1);
                    int dk_abs = dk0 + 2 * i + sel;
                    unsigned out = sel ? ((theirs >> 16) | (mine & 0xffff0000u))
                                       : ((mine & 0xffffu) | (theirs << 16));
                    unsigned byteoff = ((unsigned)(dk_abs * 128) + kvp) ^
                                       ((unsigned)(dk_abs & 7) << 4);
                    *(unsigned*)((char*)Vt + byteoff) = out;
                }
            }
            __syncthreads();

            // ---- T14: issue next tile's global loads under the compute ----
            if (j < qblk) load_kv(j + 1);

            // ---- QK^T (swapped): sacc rows = kv, cols = q ----
            f32x4 sacc[4] = {};
#pragma unroll
            for (int mf = 0; mf < 4; ++mf) {
                int row = mf * 16 + q15;
#pragma unroll
                for (int ks = 0; ks < 2; ++ks) {
                    unsigned byteoff = ((unsigned)(row * 128 + ks * 64 + g * 16)) ^
                                       ((unsigned)(row & 7) << 4);
                    short8 kf = __builtin_bit_cast(
                        short8, *(const u32x4*)((char*)Kt + byteoff));
                    sacc[mf] = __builtin_amdgcn_mfma_f32_16x16x32_bf16(
                        kf, qf[ks], sacc[mf], 0, 0, 0);
                }
            }

            // ---- mask + online softmax in log2 domain ----
            float p[4][4];
            float pmax = -1e30f;
            const bool diag = (j == qblk);
#pragma unroll
            for (int mf = 0; mf < 4; ++mf)
#pragma unroll
                for (int r = 0; r < 4; ++r) {
                    float sv = sacc[mf][r] * SCL;
                    if (diag) {
                        int kvg = j * 64 + mf * 16 + 4 * g + r;
                        if (kvg > qg) sv = -1e30f;
                    }
                    p[mf][r] = sv;
                    pmax = fmaxf(pmax, sv);
                }
            pmax = fmaxf(pmax, __shfl_xor(pmax, 16));
            pmax = fmaxf(pmax, __shfl_xor(pmax, 32));
            // T13 defer-max: only rescale when the max actually grew by >8
            if (__any(pmax > m_run + 8.f)) {
                float mnew = fmaxf(m_run, pmax);
                float corr = exp2a(m_run - mnew);
                l_run *= corr;
#pragma unroll
                for (int mf = 0; mf < 4; ++mf)
#pragma unroll
                    for (int r = 0; r < 4; ++r) xacc[mf][r] *= corr;
                m_run = mnew;
            }
            float lsum = 0.f;
#pragma unroll
            for (int mf = 0; mf < 4; ++mf)
#pragma unroll
                for (int r = 0; r < 4; ++r) {
                    float e = exp2a(p[mf][r] - m_run);
                    p[mf][r] = e;
                    lsum += e;
                }
            lsum += __shfl_xor(lsum, 16);
            lsum += __shfl_xor(lsum, 32);
            l_run += lsum;

            // ---- pack P pairs; PV as O^T = mfma(A=Vt, B=P^T) ----
            unsigned pkk[4][2];
#pragma unroll
            for (int mf = 0; mf < 4; ++mf) {
                pkk[mf][0] = pk2(p[mf][0], p[mf][1]);
                pkk[mf][1] = pk2(p[mf][2], p[mf][3]);
            }
#pragma unroll
            for (int ks = 0; ks < 2; ++ks) {
                unsigned bw[4];
#pragma unroll
                for (int w2 = 0; w2 < 4; ++w2) {
                    // dest (g,q15) needs P[q15][kv=ks*32+g*8+2*w2,+1] =
                    // pkk[2*ks+(g>>1)][w2&1] of lane g_src=2*(g&1)+(w2>>1).
                    // Shuffle BOTH mf candidates (lane-invariant indices),
                    // select on dest side (shfl evaluates on the SOURCE lane).
                    int srcl = (2 * (g & 1) + (w2 >> 1)) * 16 + q15;
                    unsigned v0 = (unsigned)__shfl((int)pkk[2 * ks][w2 & 1], srcl);
                    unsigned v1 =
                        (unsigned)__shfl((int)pkk[2 * ks + 1][w2 & 1], srcl);
                    bw[w2] = (g & 2) ? v1 : v0;
                }
                u32x4 tmp = {bw[0], bw[1], bw[2], bw[3]};
                short8 pb = __builtin_bit_cast(short8, tmp);
#pragma unroll
                for (int mf = 0; mf < 4; ++mf) {
                    int row = mf * 16 + q15;
                    unsigned byteoff = ((unsigned)(row * 128 + ks * 64 + g * 16)) ^
                                       ((unsigned)(row & 7) << 4);
                    short8 vf = __builtin_bit_cast(
                        short8, *(const u32x4*)((char*)Vt + byteoff));
                    xacc[mf] = __builtin_amdgcn_mfma_f32_16x16x32_bf16(
                        vf, pb, xacc[mf], 0, 0, 0);
                }
            }
            __syncthreads();
        }

        // ---- epilogue: lane owns q=q15 row; 4x 8B stores ----
        float inv = 1.0f / l_run;
        size_t rowbase = (size_t)(b * Sn + qblk * 64 + w * 16 + q15) * Dn + h * 64;
#pragma unroll
        for (int mf = 0; mf < 4; ++mf) {
            unsigned w0 = pk2(xacc[mf][0] * inv, xacc[mf][1] * inv);
            unsigned w1 = pk2(xacc[mf][2] * inv, xacc[mf][3] * inv);
            uint2 val = {w0, w1};
            *(uint2*)(Xb + rowbase + mf * 16 + 4 * g) = val;
        }
    }
}

// ---------------------------------------------------------------------------
// Launch. ws layout (bf16): Qb | Kb | Vb | Xb, each 8192*1024 elems = 16 MiB.
// Q/K/V head-major [B,H,S,DK]; Xb row-major [B*S, D].
// ---------------------------------------------------------------------------
extern "C" void kernel_launch(void* const* d_in, const int* in_sizes, int n_in,
                              void* d_out, int out_size, void* d_ws, size_t ws_size,
                              hipStream_t stream) {
    (void)in_sizes; (void)n_in; (void)out_size; (void)ws_size;
    const float* q = (const float*)d_in[0];
    const float* k = (const float*)d_in[1];
    const float* v = (const float*)d_in[2];
    // d_in[3] = mask (causal tril; implemented analytically)
    const float* Wq = (const float*)d_in[4];
    const float* Wk = (const float*)d_in[5];
    const float* Wv = (const float*)d_in[6];
    const float* Wo = (const float*)d_in[7];

    unsigned short* Qb = (unsigned short*)d_ws;
    unsigned short* Kb = Qb + (size_t)Mrows * Dn;
    unsigned short* Vb = Kb + (size_t)Mrows * Dn;
    unsigned short* Xb = Vb + (size_t)Mrows * Dn;

    dim3 blk(256);
    dim3 ggrid(Dn / 128, Mrows / 128);

    gemm_nt<false, false><<<ggrid, blk, 0, stream>>>((const void*)q, Wq, (void*)Qb);
    gemm_nt<false, false><<<ggrid, blk, 0, stream>>>((const void*)k, Wk, (void*)Kb);
    gemm_nt<false, false><<<ggrid, blk, 0, stream>>>((const void*)v, Wv, (void*)Vb);

    attn_fwd<<<dim3(NQB / 2, Bn * Hn), blk, 0, stream>>>(Qb, Kb, Vb, Xb);

    gemm_nt<true, true><<<ggrid, blk, 0, stream>>>((const void*)Xb, Wo, d_out);
}